// Round 8
// baseline (2898.187 us; speedup 1.0000x reference)
//
#include <hip/hip_runtime.h>

typedef unsigned int uint;

__device__ __forceinline__ float bfl(uint u){ return __uint_as_float(u << 16); }
__device__ __forceinline__ float bfh(uint u){ return __uint_as_float(u & 0xFFFF0000u); }
__device__ __forceinline__ uint f2bfbits(float f){
    uint b = __float_as_uint(f);
    return (b + 0x7FFFu + ((b >> 16) & 1u)) >> 16;
}
__device__ __forceinline__ uint packbf2(float a, float b){
    return f2bfbits(a) | (f2bfbits(b) << 16);
}
__device__ __forceinline__ int smap(int4 m, int s){
    return (s == 0) ? m.x : (s == 1) ? m.y : (s == 2) ? m.z : m.w;
}
__device__ __forceinline__ int2 ldnt(const int2* p){
    long long v = __builtin_nontemporal_load((const long long*)p);
    int2 r; r.x = (int)(v & 0xFFFFFFFFll); r.y = (int)(v >> 32); return r;
}

#define CH 6144
#define SBSHIFT 7
#define SBROWS 128
#define MAXCH 544        // >= nchunks = ceil(E/CH)
#define SBUF_CAP 5120    // bucket edge capacity in LDS (mean 4096, +16 sigma)
#define PGRID 2048

// ---------------- dense part ----------------

#define BM 64
#define BK 32
__global__ __launch_bounds__(256) void gemm_kernel(const float* __restrict__ x,
                                                   const float* __restrict__ Wa,
                                                   const float* __restrict__ Wb,
                                                   float* __restrict__ AB, int N) {
    __shared__ float xsT[BK][BM + 4];
    __shared__ float wsm[BK][256];
    int t = threadIdx.x;
    int rowbase = blockIdx.x * BM;
    int tx = t & 15, ty = t >> 4;
    float acc[4][16];
    #pragma unroll
    for (int i = 0; i < 4; i++)
        #pragma unroll
        for (int j = 0; j < 16; j++) acc[i][j] = 0.f;

    for (int k0 = 0; k0 < 256; k0 += BK) {
        {
            int r = t & 63;
            int koff = (t >> 6) * 8;
            int gr = rowbase + r; if (gr >= N) gr = N - 1;
            const float* src = x + (size_t)gr * 256 + k0 + koff;
            float4 u0 = *(const float4*)(src);
            float4 u1 = *(const float4*)(src + 4);
            xsT[koff + 0][r] = u0.x; xsT[koff + 1][r] = u0.y;
            xsT[koff + 2][r] = u0.z; xsT[koff + 3][r] = u0.w;
            xsT[koff + 4][r] = u1.x; xsT[koff + 5][r] = u1.y;
            xsT[koff + 6][r] = u1.z; xsT[koff + 7][r] = u1.w;
        }
        {
            #pragma unroll
            for (int i = 0; i < 8; i++) {
                int f = t + i * 256;
                int rr = f >> 6, c4 = f & 63;
                const float* src = (c4 < 32) ? &Wa[(size_t)(k0 + rr) * 128 + c4 * 4]
                                             : &Wb[(size_t)(k0 + rr) * 128 + (c4 - 32) * 4];
                *(float4*)&wsm[rr][c4 * 4] = *(const float4*)src;
            }
        }
        __syncthreads();
        #pragma unroll
        for (int kk = 0; kk < BK; ++kk) {
            float4 a = *(const float4*)&xsT[kk][ty * 4];
            float av[4] = {a.x, a.y, a.z, a.w};
            float bv[16];
            #pragma unroll
            for (int q = 0; q < 4; q++)
                *(float4*)&bv[q * 4] = *(const float4*)&wsm[kk][q * 64 + tx * 4];
            #pragma unroll
            for (int i = 0; i < 4; i++)
                #pragma unroll
                for (int j = 0; j < 16; j++)
                    acc[i][j] = fmaf(av[i], bv[j], acc[i][j]);
        }
        __syncthreads();
    }
    #pragma unroll
    for (int i = 0; i < 4; i++) {
        int gr = rowbase + ty * 4 + i;
        if (gr < N) {
            #pragma unroll
            for (int q = 0; q < 4; q++) {
                float4 o = {acc[i][q*4], acc[i][q*4+1], acc[i][q*4+2], acc[i][q*4+3]};
                *(float4*)&AB[(size_t)gr * 256 + q * 64 + tx * 4] = o;
            }
        }
    }
}

// attention: Pb[n] packed bf16 [N][128]
__global__ __launch_bounds__(256) void attn_kernel(const float* __restrict__ AB,
        const float* __restrict__ w1, const float* __restrict__ b1,
        const float* __restrict__ w2, uint* __restrict__ Pb, int N) {
    __shared__ float w1s[128 * 32];
    __shared__ float b1s[32], w2s[32];
    __shared__ float aS[4][128], alS[4][128];
    int t = threadIdx.x;
    #pragma unroll
    for (int i = 0; i < 16; i++) w1s[t + i * 256] = w1[t + i * 256];
    if (t < 32) { b1s[t] = b1[t]; w2s[t] = w2[t]; }

    int w = t >> 6, lane = t & 63;
    int node = blockIdx.x * 4 + w;
    bool active = node < N;
    int nclamp = active ? node : (N - 1);
    float2 a = *(const float2*)(AB + (size_t)nclamp * 256 + lane * 2);
    float2 b = *(const float2*)(AB + (size_t)nclamp * 256 + 128 + lane * 2);
    float2 al;
    al.x = a.x + 0.5f * (a.x * a.x - a.x * b.x);
    al.y = a.y + 0.5f * (a.y * a.y - a.y * b.y);
    aS[w][lane * 2] = a.x;   aS[w][lane * 2 + 1] = a.y;
    alS[w][lane * 2] = al.x; alS[w][lane * 2 + 1] = al.y;
    __syncthreads();

    int j = lane & 31;
    const float* src = (lane < 32) ? aS[w] : alS[w];
    float acc = b1s[j];
    #pragma unroll 8
    for (int d = 0; d < 128; ++d) acc = fmaf(src[d], w1s[d * 32 + j], acc);
    float h = tanhf(acc);
    float prod = h * w2s[j];
    #pragma unroll
    for (int off = 1; off < 32; off <<= 1) prod += __shfl_xor(prod, off);
    float eo = __shfl_xor(prod, 32);
    float e0 = (lane < 32) ? prod : eo;
    float e1 = (lane < 32) ? eo : prod;
    float m = fmaxf(e0, e1);
    float p0 = expf(e0 - m), p1 = expf(e1 - m);
    float inv = 1.0f / (p0 + p1);
    float at0 = p0 * inv, at1 = p1 * inv;
    if (active) {
        float px = at0 * a.x + at1 * al.x;
        float py = at0 * a.y + at1 * al.y;
        Pb[(size_t)node * 64 + lane] = packbf2(px, py);
    }
}

// ---------------- CSR build ----------------

__device__ __forceinline__ void block_scan1024(int* a, int t, int* wsum) {
    int lane = t & 63, wid = t >> 6;
    int c0 = a[t * 4], c1 = a[t * 4 + 1], c2 = a[t * 4 + 2], c3 = a[t * 4 + 3];
    int tsum = c0 + c1 + c2 + c3, incl = tsum;
    #pragma unroll
    for (int off = 1; off < 64; off <<= 1) {
        int y = __shfl_up(incl, off);
        if (lane >= off) incl += y;
    }
    if (lane == 63) wsum[wid] = incl;
    __syncthreads();
    int wb = 0;
    #pragma unroll
    for (int w = 0; w < 4; w++) if (w < wid) wb += wsum[w];
    int excl = wb + incl - tsum;
    a[t * 4] = excl; a[t * 4 + 1] = excl + c0;
    a[t * 4 + 2] = excl + c0 + c1; a[t * 4 + 3] = excl + c0 + c1 + c2;
    __syncthreads();
}

// pass A: chunk-local binning into 128-row buckets; linear stage write.
// olTab layout [s][chunk][bucket], packed off|len<<16. gtot accumulated via
// fire-and-forget atomics (no return value -> no wave stall).
__global__ __launch_bounds__(256) void fill_chunk(const int* __restrict__ rows,
        const int* __restrict__ cols, const float* __restrict__ vals, int4 map,
        int2* __restrict__ stage, int* __restrict__ olTab, int* __restrict__ gtot,
        int NSB, int nchunks, int E) {
    __shared__ int2 sbuf[CH];
    __shared__ int hist[1024];
    __shared__ int wsum[4];
    int c = blockIdx.x, s = blockIdx.y, t = threadIdx.x;
    int lane = t & 63, wid = t >> 6;
    size_t sb = (size_t)smap(map, s) * E;
    int e0 = c * CH;
    int e1 = e0 + CH; if (e1 > E) e1 = E;
    int csz = e1 - e0;
    #pragma unroll
    for (int k = 0; k < 4; k++) hist[t + k * 256] = 0;
    __syncthreads();
    for (int e = e0 + t; e < e1; e += 256)
        atomicAdd(&hist[(uint)rows[sb + e] >> SBSHIFT], 1);
    __syncthreads();
    // 1024-wide scan + table emit
    {
        int idx = t * 4;
        int c0 = hist[idx], c1 = hist[idx + 1], c2 = hist[idx + 2], c3 = hist[idx + 3];
        int tsum = c0 + c1 + c2 + c3, incl = tsum;
        #pragma unroll
        for (int off = 1; off < 64; off <<= 1) {
            int y = __shfl_up(incl, off);
            if (lane >= off) incl += y;
        }
        if (lane == 63) wsum[wid] = incl;
        __syncthreads();
        int wb = 0;
        #pragma unroll
        for (int w = 0; w < 4; w++) if (w < wid) wb += wsum[w];
        int ex = wb + incl - tsum;
        int offs[4] = {ex, ex + c0, ex + c0 + c1, ex + c0 + c1 + c2};
        int lens[4] = {c0, c1, c2, c3};
        hist[idx] = offs[0]; hist[idx + 1] = offs[1];
        hist[idx + 2] = offs[2]; hist[idx + 3] = offs[3];
        size_t tb = ((size_t)s * nchunks + c) * NSB;
        #pragma unroll
        for (int k = 0; k < 4; k++) {
            int bkt = idx + k;
            if (bkt < NSB) {
                olTab[tb + bkt] = offs[k] | (lens[k] << 16);
                if (lens[k]) atomicAdd(&gtot[s * NSB + bkt], lens[k]);
            }
        }
    }
    __syncthreads();
    for (int e = e0 + t; e < e1; e += 256) {
        int r = rows[sb + e];
        int pos = atomicAdd(&hist[(uint)r >> SBSHIFT], 1);
        uint cw = (uint)cols[sb + e] | ((uint)(r & (SBROWS - 1)) << 20);
        sbuf[pos] = make_int2((int)cw, __float_as_int(vals[sb + e]));
    }
    __syncthreads();
    int2* dst = stage + (size_t)s * E + e0;
    for (int i = t; i < csz; i += 256)
        __builtin_nontemporal_store(*(const long long*)&sbuf[i], (long long*)&dst[i]);
}

// exclusive scan of bucket totals -> bucket bases (one block per support)
__global__ __launch_bounds__(256) void bucket_scanex(const int* __restrict__ gtot,
        int* __restrict__ bbase, int NSB) {
    __shared__ int a[1024];
    __shared__ int wsum[4];
    int s = blockIdx.x, t = threadIdx.x;
    #pragma unroll
    for (int k = 0; k < 4; k++) {
        int i = t + k * 256;
        a[i] = (i < NSB) ? gtot[s * NSB + i] : 0;
    }
    __syncthreads();
    block_scan1024(a, t, wsum);
    #pragma unroll
    for (int k = 0; k < 4; k++) {
        int i = t + k * 256;
        if (i < NSB) bbase[s * NSB + i] = a[i];
    }
}

// pass B: block per (128-row bucket, support). All placement in LDS; pk written
// with ONE linear pass (write amplification 1). Rows col-sorted in LDS.
__global__ __launch_bounds__(256) void fill_bucket(const int2* __restrict__ stage,
        const int* __restrict__ olTab, const int* __restrict__ bbase,
        int* __restrict__ rp, int2* __restrict__ pk,
        int NSB, int nchunks, int N, int E) {
    __shared__ int2 sbuf[SBUF_CAP];
    __shared__ int stab[MAXCH];
    __shared__ int loc[130];
    __shared__ int cur[128];
    __shared__ int wsum2[2];
    int b = blockIdx.x, s = blockIdx.y, t = threadIdx.x;
    int rowbase = b << SBSHIFT;
    int nrows = N - rowbase; if (nrows > SBROWS) nrows = SBROWS;
    int wid = t >> 6, lane = t & 63;

    for (int i = t; i < nchunks; i += 256)
        stab[i] = olTab[((size_t)s * nchunks + i) * NSB + b];
    if (t < 128) cur[t] = 0;
    __syncthreads();

    size_t sb = (size_t)s * E;
    // phase 1: local-row histogram (4-way MLP over segments)
    for (int c0 = wid; c0 < nchunks; c0 += 16) {
        const int2* sp[4]; int ll[4]; int2 uu[4];
        #pragma unroll
        for (int k = 0; k < 4; k++) {
            int cc = c0 + k * 4;
            ll[k] = 0; sp[k] = stage;
            if (cc < nchunks) {
                int p = stab[cc];
                ll[k] = p >> 16;
                sp[k] = stage + sb + (size_t)cc * CH + (p & 0xFFFF);
                uu[k] = (lane < ll[k]) ? sp[k][lane] : make_int2(0, 0);
            }
        }
        #pragma unroll
        for (int k = 0; k < 4; k++) {
            if (lane < ll[k]) atomicAdd(&cur[((uint)uu[k].x) >> 20], 1);
            for (int i = lane + 64; i < ll[k]; i += 64)
                atomicAdd(&cur[((uint)sp[k][i].x) >> 20], 1);
        }
    }
    __syncthreads();

    // phase 2: 128-scan -> local offsets + rp
    int bb = bbase[s * NSB + b];
    int v = 0, incl = 0;
    if (t < 128) {
        v = cur[t]; incl = v;
        #pragma unroll
        for (int off = 1; off < 64; off <<= 1) {
            int y = __shfl_up(incl, off);
            if (lane >= off) incl += y;
        }
        if (lane == 63) wsum2[wid] = incl;
    }
    __syncthreads();
    if (t < 128) {
        int excl = incl - v + ((wid == 1) ? wsum2[0] : 0);
        loc[t] = excl; cur[t] = excl;
        if (t < nrows) rp[(size_t)s * (N + 1) + rowbase + t] = bb + excl;
    }
    if (t == 0) loc[128] = wsum2[0] + wsum2[1];
    if (b == 0 && t == 0) rp[(size_t)s * (N + 1) + N] = E;
    __syncthreads();

    // phase 2b: placement into LDS sbuf (4-way MLP)
    for (int c0 = wid; c0 < nchunks; c0 += 16) {
        const int2* sp[4]; int ll[4]; int2 uu[4];
        #pragma unroll
        for (int k = 0; k < 4; k++) {
            int cc = c0 + k * 4;
            ll[k] = 0; sp[k] = stage;
            if (cc < nchunks) {
                int p = stab[cc];
                ll[k] = p >> 16;
                sp[k] = stage + sb + (size_t)cc * CH + (p & 0xFFFF);
                uu[k] = (lane < ll[k]) ? sp[k][lane] : make_int2(0, 0);
            }
        }
        #pragma unroll
        for (int k = 0; k < 4; k++) {
            if (lane < ll[k]) {
                int2 u = uu[k];
                int pos = atomicAdd(&cur[((uint)u.x) >> 20], 1);
                int2 w = make_int2(u.x & 0xFFFFF, u.y);
                if (pos < SBUF_CAP) sbuf[pos] = w; else pk[sb + bb + pos] = w;
            }
            for (int i = lane + 64; i < ll[k]; i += 64) {
                int2 u = sp[k][i];
                int pos = atomicAdd(&cur[((uint)u.x) >> 20], 1);
                int2 w = make_int2(u.x & 0xFFFFF, u.y);
                if (pos < SBUF_CAP) sbuf[pos] = w; else pk[sb + bb + pos] = w;
            }
        }
    }
    __syncthreads();

    // phase 3: per-row bitonic col-sort in LDS (wave per row)
    int tot = loc[128];
    for (int r = wid; r < nrows; r += 4) {
        int beg = loc[r], end = loc[r + 1];
        int deg = end - beg;
        if (deg < 2 || deg > 64 || end > SBUF_CAP) continue;
        int key = 0x7FFFFFFF, val = 0;
        if (lane < deg) { int2 u = sbuf[beg + lane]; key = u.x; val = u.y; }
        #pragma unroll
        for (int k = 2; k <= 64; k <<= 1) {
            #pragma unroll
            for (int j = k >> 1; j > 0; j >>= 1) {
                int okey = __shfl_xor(key, j);
                int oval = __shfl_xor(val, j);
                bool up = ((lane & k) == 0);
                bool lower = ((lane & j) == 0);
                bool keepmin = (lower == up);
                bool take = keepmin ? (okey < key) : (okey > key);
                if (take) { key = okey; val = oval; }
            }
        }
        if (lane < deg) sbuf[beg + lane] = make_int2(key, val);
    }
    __syncthreads();

    // phase 4: linear pk write
    int lim = (tot < SBUF_CAP) ? tot : SBUF_CAP;
    for (int i = t; i < lim; i += 256)
        __builtin_nontemporal_store(*(const long long*)&sbuf[i], (long long*)&pk[sb + bb + i]);
}

// ---------------- fused SpMM kernels (persistent, sorted-walk, MLP=4) ----------------

__device__ __forceinline__ void row_gather_sum(const int2* __restrict__ pk,
        int e, int end, const uint* __restrict__ Xb, int lane,
        float& ax, float& ay) {
    for (; e + 4 <= end; e += 4) {
        int2 c0 = ldnt(&pk[e]);     int2 c1 = ldnt(&pk[e + 1]);
        int2 c2 = ldnt(&pk[e + 2]); int2 c3 = ldnt(&pk[e + 3]);
        uint u0 = Xb[(c0.x << 6) + lane]; uint u1 = Xb[(c1.x << 6) + lane];
        uint u2 = Xb[(c2.x << 6) + lane]; uint u3 = Xb[(c3.x << 6) + lane];
        float v0 = __int_as_float(c0.y), v1 = __int_as_float(c1.y);
        float v2 = __int_as_float(c2.y), v3 = __int_as_float(c3.y);
        ax = fmaf(v0, bfl(u0), ax); ay = fmaf(v0, bfh(u0), ay);
        ax = fmaf(v1, bfl(u1), ax); ay = fmaf(v1, bfh(u1), ay);
        ax = fmaf(v2, bfl(u2), ax); ay = fmaf(v2, bfh(u2), ay);
        ax = fmaf(v3, bfl(u3), ax); ay = fmaf(v3, bfh(u3), ay);
    }
    for (; e < end; ++e) {
        int2 c0 = ldnt(&pk[e]);
        uint u0 = Xb[(c0.x << 6) + lane];
        float v0 = __int_as_float(c0.y);
        ax = fmaf(v0, bfl(u0), ax); ay = fmaf(v0, bfh(u0), ay);
    }
}

__device__ __forceinline__ void row_gather_bp(const int2* __restrict__ pk,
        int e, int end, const uint* __restrict__ Xb, int lane,
        float& sx, float& sy, float& qx, float& qy) {
    for (; e + 4 <= end; e += 4) {
        int2 c0 = ldnt(&pk[e]);     int2 c1 = ldnt(&pk[e + 1]);
        int2 c2 = ldnt(&pk[e + 2]); int2 c3 = ldnt(&pk[e + 3]);
        uint u0 = Xb[(c0.x << 6) + lane]; uint u1 = Xb[(c1.x << 6) + lane];
        uint u2 = Xb[(c2.x << 6) + lane]; uint u3 = Xb[(c3.x << 6) + lane];
        float v0 = __int_as_float(c0.y), v1 = __int_as_float(c1.y);
        float v2 = __int_as_float(c2.y), v3 = __int_as_float(c3.y);
        float x0 = bfl(u0), y0 = bfh(u0), x1 = bfl(u1), y1 = bfh(u1);
        float x2 = bfl(u2), y2 = bfh(u2), x3 = bfl(u3), y3 = bfh(u3);
        sx = fmaf(v0, x0, sx); sy = fmaf(v0, y0, sy);
        qx = fmaf(v0 * x0, x0, qx); qy = fmaf(v0 * y0, y0, qy);
        sx = fmaf(v1, x1, sx); sy = fmaf(v1, y1, sy);
        qx = fmaf(v1 * x1, x1, qx); qy = fmaf(v1 * y1, y1, qy);
        sx = fmaf(v2, x2, sx); sy = fmaf(v2, y2, sy);
        qx = fmaf(v2 * x2, x2, qx); qy = fmaf(v2 * y2, y2, qy);
        sx = fmaf(v3, x3, sx); sy = fmaf(v3, y3, sy);
        qx = fmaf(v3 * x3, x3, qx); qy = fmaf(v3 * y3, y3, qy);
    }
    for (; e < end; ++e) {
        int2 c0 = ldnt(&pk[e]);
        uint u0 = Xb[(c0.x << 6) + lane];
        float v0 = __int_as_float(c0.y);
        float x0 = bfl(u0), y0 = bfh(u0);
        sx = fmaf(v0, x0, sx); sy = fmaf(v0, y0, sy);
        qx = fmaf(v0 * x0, x0, qx); qy = fmaf(v0 * y0, y0, qy);
    }
}

__global__ __launch_bounds__(256) void spmm_bp2(const int* __restrict__ rpA,
        const int2* __restrict__ pkA, const int* __restrict__ rpB,
        const int2* __restrict__ pkB, const uint* __restrict__ Xb,
        uint* __restrict__ outb, int N) {
    int w = threadIdx.x >> 6, lane = threadIdx.x & 63;
    int stride = gridDim.x * 4;
    for (int row = blockIdx.x * 4 + w; row < N; row += stride) {
        float sax = 0.f, say = 0.f, qax = 0.f, qay = 0.f;
        float sbx = 0.f, sby = 0.f, qbx = 0.f, qby = 0.f;
        row_gather_bp(pkA, rpA[row], rpA[row + 1], Xb, lane, sax, say, qax, qay);
        row_gather_bp(pkB, rpB[row], rpB[row + 1], Xb, lane, sbx, sby, qbx, qby);
        float tx = 0.5f * ((sax * sax - qax) - (sbx * sbx - qbx));
        float ty = 0.5f * ((say * say - qay) - (sby * sby - qby));
        outb[((size_t)row << 6) + lane] = packbf2(tx, ty);
    }
}

__global__ __launch_bounds__(256) void spmm_out(const int* __restrict__ rp0,
        const int2* __restrict__ pk0, const int* __restrict__ rp5,
        const int2* __restrict__ pk5, const int* __restrict__ rp6,
        const int2* __restrict__ pk6, const uint* __restrict__ Pb,
        const uint* __restrict__ t1b, const uint* __restrict__ t2b,
        float* __restrict__ out, int N) {
    int w = threadIdx.x >> 6, lane = threadIdx.x & 63;
    int stride = gridDim.x * 4;
    for (int row = blockIdx.x * 4 + w; row < N; row += stride) {
        float a0x = 0.f, a0y = 0.f, a5x = 0.f, a5y = 0.f, a6x = 0.f, a6y = 0.f;
        row_gather_sum(pk0, rp0[row], rp0[row + 1], Pb,  lane, a0x, a0y);
        row_gather_sum(pk5, rp5[row], rp5[row + 1], t1b, lane, a5x, a5y);
        row_gather_sum(pk6, rp6[row], rp6[row + 1], t2b, lane, a6x, a6y);
        float rx = fmaxf(0.5f * a0x + 0.25f * a5x + 0.25f * a6x, 0.f);
        float ry = fmaxf(0.5f * a0y + 0.25f * a5y + 0.25f * a6y, 0.f);
        *(float2*)(out + ((size_t)row << 7) + (lane << 1)) = make_float2(rx, ry);
    }
}

// ---------------- launch ----------------

extern "C" void kernel_launch(void* const* d_in, const int* in_sizes, int n_in,
                              void* d_out, int out_size, void* d_ws, size_t ws_size,
                              hipStream_t stream) {
    (void)n_in; (void)out_size; (void)ws_size;
    const float* x   = (const float*)d_in[0];
    const float* Wa  = (const float*)d_in[1];
    const float* Wb  = (const float*)d_in[2];
    const float* w1  = (const float*)d_in[4];
    const float* b1  = (const float*)d_in[5];
    const float* w2  = (const float*)d_in[6];
    const int* rows  = (const int*)d_in[7];
    const int* cols  = (const int*)d_in[8];
    const float* vals = (const float*)d_in[9];
    float* out = (float*)d_out;

    const int N = in_sizes[0] / 256;
    const int E = in_sizes[7] / 7;
    const int NSB = (N + SBROWS - 1) >> SBSHIFT;
    const int nchunks = (E + CH - 1) / CH;

    uint* Pb  = (uint*)d_ws;
    uint* t1b = Pb + (size_t)N * 64;
    uint* t2b = t1b + (size_t)N * 64;
    int2* pk  = (int2*)(t2b + (size_t)N * 64);
    size_t regionFloats = (size_t)N * 256;
    if ((size_t)8 * E > regionFloats) regionFloats = (size_t)8 * E;
    int2* stage = pk + (size_t)4 * E;
    float* AB   = (float*)stage;
    int* rp     = (int*)((float*)stage + regionFloats);
    int* olTab  = rp + 4 * (size_t)(N + 1);
    int* gtot   = olTab + (size_t)4 * nchunks * NSB;
    int* bbase  = gtot + (size_t)4 * NSB;

    dim3 b256(256);
    int sgrid = (N + 3) / 4;
    int pgrid = PGRID; if (pgrid > sgrid) pgrid = sgrid;

    gemm_kernel<<<(N + BM - 1) / BM, b256, 0, stream>>>(x, Wa, Wb, AB, N);
    attn_kernel<<<sgrid, b256, 0, stream>>>(AB, w1, b1, w2, Pb, N);

    auto build = [&](int4 map, int nsup) {
        hipMemsetAsync(gtot, 0, (size_t)nsup * NSB * sizeof(int), stream);
        fill_chunk<<<dim3(nchunks, nsup), b256, 0, stream>>>(rows, cols, vals, map,
                                                             stage, olTab, gtot, NSB, nchunks, E);
        bucket_scanex<<<nsup, b256, 0, stream>>>(gtot, bbase, NSB);
        fill_bucket<<<dim3(NSB, nsup), b256, 0, stream>>>(stage, olTab, bbase,
                                                          rp, pk, NSB, nchunks, N, E);
    };

    const int NP1 = N + 1;

    // group A: slots {1,3,2,4}
    build(make_int4(1, 3, 2, 4), 4);
    spmm_bp2<<<pgrid, b256, 0, stream>>>(rp + 0 * NP1, pk + 0 * (size_t)E,
                                         rp + 1 * NP1, pk + 1 * (size_t)E, Pb, t1b, N);
    spmm_bp2<<<pgrid, b256, 0, stream>>>(rp + 2 * NP1, pk + 2 * (size_t)E,
                                         rp + 3 * NP1, pk + 3 * (size_t)E, Pb, t2b, N);

    // group B: slots {0,5,6}
    build(make_int4(0, 5, 6, 6), 3);
    spmm_out<<<pgrid, b256, 0, stream>>>(rp + 0 * NP1, pk + 0 * (size_t)E,
                                         rp + 1 * NP1, pk + 1 * (size_t)E,
                                         rp + 2 * NP1, pk + 2 * (size_t)E,
                                         Pb, t1b, t2b, out, N);
}

// Round 9
// 2211.772 us; speedup vs baseline: 1.3103x; 1.3103x over previous
//
#include <hip/hip_runtime.h>

typedef unsigned int uint;
typedef unsigned short ushort;

__device__ __forceinline__ float bfl(uint u){ return __uint_as_float(u << 16); }
__device__ __forceinline__ float bfh(uint u){ return __uint_as_float(u & 0xFFFF0000u); }
__device__ __forceinline__ uint f2bfbits(float f){
    uint b = __float_as_uint(f);
    return (b + 0x7FFFu + ((b >> 16) & 1u)) >> 16;
}
__device__ __forceinline__ uint packbf2(float a, float b){
    return f2bfbits(a) | (f2bfbits(b) << 16);
}
__device__ __forceinline__ int smap(int4 m, int s){
    return (s == 0) ? m.x : (s == 1) ? m.y : (s == 2) ? m.z : m.w;
}
__device__ __forceinline__ int2 ldnt(const int2* p){
    long long v = __builtin_nontemporal_load((const long long*)p);
    int2 r; r.x = (int)(v & 0xFFFFFFFFll); r.y = (int)(v >> 32); return r;
}

#define CH 6144
#define SBSHIFT 7
#define SBROWS 128
#define HISTP 784        // padded bucket-hist size (NSB<=782)
#define SBUF_CAP 5120    // LDS bucket capacity (mean 4096, +16 sigma)
#define PGRID 2048

// ---------------- dense part ----------------

#define BM 64
#define BK 32
__global__ __launch_bounds__(256) void gemm_kernel(const float* __restrict__ x,
                                                   const float* __restrict__ Wa,
                                                   const float* __restrict__ Wb,
                                                   float* __restrict__ AB, int N) {
    __shared__ float xsT[BK][BM + 4];
    __shared__ float wsm[BK][256];
    int t = threadIdx.x;
    int rowbase = blockIdx.x * BM;
    int tx = t & 15, ty = t >> 4;
    float acc[4][16];
    #pragma unroll
    for (int i = 0; i < 4; i++)
        #pragma unroll
        for (int j = 0; j < 16; j++) acc[i][j] = 0.f;

    for (int k0 = 0; k0 < 256; k0 += BK) {
        {
            int r = t & 63;
            int koff = (t >> 6) * 8;
            int gr = rowbase + r; if (gr >= N) gr = N - 1;
            const float* src = x + (size_t)gr * 256 + k0 + koff;
            float4 u0 = *(const float4*)(src);
            float4 u1 = *(const float4*)(src + 4);
            xsT[koff + 0][r] = u0.x; xsT[koff + 1][r] = u0.y;
            xsT[koff + 2][r] = u0.z; xsT[koff + 3][r] = u0.w;
            xsT[koff + 4][r] = u1.x; xsT[koff + 5][r] = u1.y;
            xsT[koff + 6][r] = u1.z; xsT[koff + 7][r] = u1.w;
        }
        {
            #pragma unroll
            for (int i = 0; i < 8; i++) {
                int f = t + i * 256;
                int rr = f >> 6, c4 = f & 63;
                const float* src = (c4 < 32) ? &Wa[(size_t)(k0 + rr) * 128 + c4 * 4]
                                             : &Wb[(size_t)(k0 + rr) * 128 + (c4 - 32) * 4];
                *(float4*)&wsm[rr][c4 * 4] = *(const float4*)src;
            }
        }
        __syncthreads();
        #pragma unroll
        for (int kk = 0; kk < BK; ++kk) {
            float4 a = *(const float4*)&xsT[kk][ty * 4];
            float av[4] = {a.x, a.y, a.z, a.w};
            float bv[16];
            #pragma unroll
            for (int q = 0; q < 4; q++)
                *(float4*)&bv[q * 4] = *(const float4*)&wsm[kk][q * 64 + tx * 4];
            #pragma unroll
            for (int i = 0; i < 4; i++)
                #pragma unroll
                for (int j = 0; j < 16; j++)
                    acc[i][j] = fmaf(av[i], bv[j], acc[i][j]);
        }
        __syncthreads();
    }
    #pragma unroll
    for (int i = 0; i < 4; i++) {
        int gr = rowbase + ty * 4 + i;
        if (gr < N) {
            #pragma unroll
            for (int q = 0; q < 4; q++) {
                float4 o = {acc[i][q*4], acc[i][q*4+1], acc[i][q*4+2], acc[i][q*4+3]};
                *(float4*)&AB[(size_t)gr * 256 + q * 64 + tx * 4] = o;
            }
        }
    }
}

// attention: Pb[n] packed bf16 [N][128]
__global__ __launch_bounds__(256) void attn_kernel(const float* __restrict__ AB,
        const float* __restrict__ w1, const float* __restrict__ b1,
        const float* __restrict__ w2, uint* __restrict__ Pb, int N) {
    __shared__ float w1s[128 * 32];
    __shared__ float b1s[32], w2s[32];
    __shared__ float aS[4][128], alS[4][128];
    int t = threadIdx.x;
    #pragma unroll
    for (int i = 0; i < 16; i++) w1s[t + i * 256] = w1[t + i * 256];
    if (t < 32) { b1s[t] = b1[t]; w2s[t] = w2[t]; }

    int w = t >> 6, lane = t & 63;
    int node = blockIdx.x * 4 + w;
    bool active = node < N;
    int nclamp = active ? node : (N - 1);
    float2 a = *(const float2*)(AB + (size_t)nclamp * 256 + lane * 2);
    float2 b = *(const float2*)(AB + (size_t)nclamp * 256 + 128 + lane * 2);
    float2 al;
    al.x = a.x + 0.5f * (a.x * a.x - a.x * b.x);
    al.y = a.y + 0.5f * (a.y * a.y - a.y * b.y);
    aS[w][lane * 2] = a.x;   aS[w][lane * 2 + 1] = a.y;
    alS[w][lane * 2] = al.x; alS[w][lane * 2 + 1] = al.y;
    __syncthreads();

    int j = lane & 31;
    const float* src = (lane < 32) ? aS[w] : alS[w];
    float acc = b1s[j];
    #pragma unroll 8
    for (int d = 0; d < 128; ++d) acc = fmaf(src[d], w1s[d * 32 + j], acc);
    float h = tanhf(acc);
    float prod = h * w2s[j];
    #pragma unroll
    for (int off = 1; off < 32; off <<= 1) prod += __shfl_xor(prod, off);
    float eo = __shfl_xor(prod, 32);
    float e0 = (lane < 32) ? prod : eo;
    float e1 = (lane < 32) ? eo : prod;
    float m = fmaxf(e0, e1);
    float p0 = expf(e0 - m), p1 = expf(e1 - m);
    float inv = 1.0f / (p0 + p1);
    float at0 = p0 * inv, at1 = p1 * inv;
    if (active) {
        float px = at0 * a.x + at1 * al.x;
        float py = at0 * a.y + at1 * al.y;
        Pb[(size_t)node * 64 + lane] = packbf2(px, py);
    }
}

// ---------------- CSR build (bucket-major reorder, zero global atomics) ----------------

__device__ __forceinline__ void block_scan1024(int* a, int t, int* wsum) {
    int lane = t & 63, wid = t >> 6;
    int c0 = a[t * 4], c1 = a[t * 4 + 1], c2 = a[t * 4 + 2], c3 = a[t * 4 + 3];
    int tsum = c0 + c1 + c2 + c3, incl = tsum;
    #pragma unroll
    for (int off = 1; off < 64; off <<= 1) {
        int y = __shfl_up(incl, off);
        if (lane >= off) incl += y;
    }
    if (lane == 63) wsum[wid] = incl;
    __syncthreads();
    int wb = 0;
    #pragma unroll
    for (int w = 0; w < 4; w++) if (w < wid) wb += wsum[w];
    int excl = wb + incl - tsum;
    a[t * 4] = excl; a[t * 4 + 1] = excl + c0;
    a[t * 4 + 2] = excl + c0 + c1; a[t * 4 + 3] = excl + c0 + c1 + c2;
    __syncthreads();
}

// 1: per-(chunk,bucket) edge counts
__global__ __launch_bounds__(256) void count_chunk(const int* __restrict__ rows, int4 map,
        int* __restrict__ lenTab, int* __restrict__ gtot, int NSB, int nchunks, int E) {
    __shared__ int hist[HISTP];
    int c = blockIdx.x, s = blockIdx.y, t = threadIdx.x;
    size_t sb = (size_t)smap(map, s) * E;
    int e0 = c * CH, e1 = e0 + CH; if (e1 > E) e1 = E;
    for (int i = t; i < HISTP; i += 256) hist[i] = 0;
    __syncthreads();
    for (int e = e0 + t; e < e1; e += 256)
        atomicAdd(&hist[(uint)rows[sb + e] >> SBSHIFT], 1);
    __syncthreads();
    for (int b = t; b < NSB; b += 256) {
        int l = hist[b];
        lenTab[((size_t)s * NSB + b) * nchunks + c] = l;
        if (l) atomicAdd(&gtot[s * NSB + b], l);
    }
}

// 2: bucket bases (exclusive scan of totals, + sentinel)
__global__ __launch_bounds__(256) void bucket_scanex(const int* __restrict__ gtot,
        int* __restrict__ bbase, int NSB) {
    __shared__ int a[1024];
    __shared__ int wsum[4];
    int s = blockIdx.x, t = threadIdx.x;
    #pragma unroll
    for (int k = 0; k < 4; k++) {
        int i = t + k * 256;
        a[i] = (i < NSB) ? gtot[s * NSB + i] : 0;
    }
    __syncthreads();
    block_scan1024(a, t, wsum);
    #pragma unroll
    for (int k = 0; k < 4; k++) {
        int i = t + k * 256;
        if (i <= NSB) bbase[s * (NSB + 1) + i] = a[i];
    }
}

// 3: per-(bucket,chunk) segment positions (prefix over chunks); wave per bucket
__global__ __launch_bounds__(64) void pos_scan(const int* __restrict__ lenTab,
        const int* __restrict__ bbase, int* __restrict__ segPos, int NSB, int nchunks) {
    int b = blockIdx.x, s = blockIdx.y, lane = threadIdx.x;
    const int* lt = lenTab + ((size_t)s * NSB + b) * nchunks;
    int* sp = segPos + ((size_t)s * NSB + b) * nchunks;
    int run = bbase[s * (NSB + 1) + b];
    for (int c0 = 0; c0 < nchunks; c0 += 64) {
        int c = c0 + lane;
        int v = (c < nchunks) ? lt[c] : 0;
        int incl = v;
        #pragma unroll
        for (int off = 1; off < 64; off <<= 1) {
            int y = __shfl_up(incl, off);
            if (lane >= off) incl += y;
        }
        if (c < nchunks) sp[c] = run + incl - v;
        run += __shfl(incl, 63);
    }
}

// 4: bin chunk in LDS, write bucket-major stage2 at precomputed slots (coalesced granules)
__global__ __launch_bounds__(256) void place_chunk(const int* __restrict__ rows,
        const int* __restrict__ cols, const float* __restrict__ vals, int4 map,
        const int* __restrict__ segPos, int2* __restrict__ stage2,
        int NSB, int nchunks, int E) {
    __shared__ int2 sbuf[CH];
    __shared__ ushort bmap[CH];
    __shared__ int cur[1024];
    __shared__ int off[1024];
    __shared__ int spos[HISTP];
    __shared__ int wsum[4];
    int c = blockIdx.x, s = blockIdx.y, t = threadIdx.x;
    size_t sb = (size_t)smap(map, s) * E;
    int e0 = c * CH, e1 = e0 + CH; if (e1 > E) e1 = E;
    int csz = e1 - e0;
    #pragma unroll
    for (int k = 0; k < 4; k++) cur[t + k * 256] = 0;
    __syncthreads();
    for (int e = e0 + t; e < e1; e += 256)
        atomicAdd(&cur[(uint)rows[sb + e] >> SBSHIFT], 1);
    __syncthreads();
    block_scan1024(cur, t, wsum);       // cur -> exclusive offsets
    #pragma unroll
    for (int k = 0; k < 4; k++) { int i = t + k * 256; off[i] = cur[i]; }
    for (int b = t; b < NSB; b += 256)
        spos[b] = segPos[((size_t)s * NSB + b) * nchunks + c];
    __syncthreads();
    for (int e = e0 + t; e < e1; e += 256) {
        int r = rows[sb + e];
        int b = (uint)r >> SBSHIFT;
        int pos = atomicAdd(&cur[b], 1);
        uint cw = (uint)cols[sb + e] | ((uint)(r & (SBROWS - 1)) << 20);
        sbuf[pos] = make_int2((int)cw, __float_as_int(vals[sb + e]));
        bmap[pos] = (ushort)b;
    }
    __syncthreads();
    int2* dst = stage2 + (size_t)s * E;
    for (int i = t; i < csz; i += 256) {
        int b = bmap[i];
        dst[spos[b] + (i - off[b])] = sbuf[i];
    }
}

// 5: bucket is contiguous in stage2 -> LDS place + row col-sort + linear pk write
__global__ __launch_bounds__(256) void fill_bucket(const int2* __restrict__ stage2,
        const int* __restrict__ bbase, int* __restrict__ rp, int2* __restrict__ pk,
        int NSB, int N, int E) {
    __shared__ int2 sbuf[SBUF_CAP];
    __shared__ int cur[128];
    __shared__ int loc[132];
    __shared__ int wsum2[2];
    int b = blockIdx.x, s = blockIdx.y, t = threadIdx.x;
    int lane = t & 63, wid = t >> 6;
    int rowbase = b << SBSHIFT;
    int nrows = N - rowbase; if (nrows > SBROWS) nrows = SBROWS;
    size_t sb = (size_t)s * E;
    int beg = bbase[s * (NSB + 1) + b];
    int end = bbase[s * (NSB + 1) + b + 1];
    int tot = end - beg;
    if (t < 128) cur[t] = 0;
    __syncthreads();
    // pass 1: contiguous read, row histogram
    for (int i = beg + t; i < end; i += 256)
        atomicAdd(&cur[((uint)stage2[sb + i].x) >> 20], 1);
    __syncthreads();
    // 128-wide scan
    int v = 0, incl = 0;
    if (t < 128) {
        v = cur[t]; incl = v;
        #pragma unroll
        for (int off = 1; off < 64; off <<= 1) {
            int y = __shfl_up(incl, off);
            if (lane >= off) incl += y;
        }
        if (lane == 63) wsum2[wid] = incl;
    }
    __syncthreads();
    if (t < 128) {
        int excl = incl - v + ((wid == 1) ? wsum2[0] : 0);
        loc[t] = excl; cur[t] = excl;
        if (t < nrows) rp[(size_t)s * (N + 1) + rowbase + t] = beg + excl;
    }
    if (t == 0) loc[128] = tot;
    if (b == 0 && t == 0) rp[(size_t)s * (N + 1) + N] = E;
    __syncthreads();
    // pass 2: contiguous re-read (L2-hot), place into LDS by row
    for (int i = beg + t; i < end; i += 256) {
        int2 u = stage2[sb + i];
        int lr = ((uint)u.x) >> 20;
        int pos = atomicAdd(&cur[lr], 1);
        int2 w = make_int2(u.x & 0xFFFFF, u.y);
        if (pos < SBUF_CAP) sbuf[pos] = w; else pk[sb + beg + pos] = w;
    }
    __syncthreads();
    // per-row bitonic col-sort in LDS (wave per row)
    for (int r = wid; r < nrows; r += 4) {
        int rb = loc[r], re = loc[r + 1];
        int deg = re - rb;
        if (deg < 2 || deg > 64 || re > SBUF_CAP) continue;
        int key = 0x7FFFFFFF, val = 0;
        if (lane < deg) { int2 u = sbuf[rb + lane]; key = u.x; val = u.y; }
        #pragma unroll
        for (int k = 2; k <= 64; k <<= 1) {
            #pragma unroll
            for (int j = k >> 1; j > 0; j >>= 1) {
                int okey = __shfl_xor(key, j);
                int oval = __shfl_xor(val, j);
                bool up = ((lane & k) == 0);
                bool lower = ((lane & j) == 0);
                bool keepmin = (lower == up);
                bool take = keepmin ? (okey < key) : (okey > key);
                if (take) { key = okey; val = oval; }
            }
        }
        if (lane < deg) sbuf[rb + lane] = make_int2(key, val);
    }
    __syncthreads();
    // linear pk write (amplification 1)
    int lim = (tot < SBUF_CAP) ? tot : SBUF_CAP;
    for (int i = t; i < lim; i += 256)
        __builtin_nontemporal_store(*(const long long*)&sbuf[i], (long long*)&pk[sb + beg + i]);
}

// ---------------- fused SpMM kernels (persistent, sorted-walk, MLP=4) ----------------

__device__ __forceinline__ void row_gather_sum(const int2* __restrict__ pk,
        int e, int end, const uint* __restrict__ Xb, int lane,
        float& ax, float& ay) {
    for (; e + 4 <= end; e += 4) {
        int2 c0 = ldnt(&pk[e]);     int2 c1 = ldnt(&pk[e + 1]);
        int2 c2 = ldnt(&pk[e + 2]); int2 c3 = ldnt(&pk[e + 3]);
        uint u0 = Xb[(c0.x << 6) + lane]; uint u1 = Xb[(c1.x << 6) + lane];
        uint u2 = Xb[(c2.x << 6) + lane]; uint u3 = Xb[(c3.x << 6) + lane];
        float v0 = __int_as_float(c0.y), v1 = __int_as_float(c1.y);
        float v2 = __int_as_float(c2.y), v3 = __int_as_float(c3.y);
        ax = fmaf(v0, bfl(u0), ax); ay = fmaf(v0, bfh(u0), ay);
        ax = fmaf(v1, bfl(u1), ax); ay = fmaf(v1, bfh(u1), ay);
        ax = fmaf(v2, bfl(u2), ax); ay = fmaf(v2, bfh(u2), ay);
        ax = fmaf(v3, bfl(u3), ax); ay = fmaf(v3, bfh(u3), ay);
    }
    for (; e < end; ++e) {
        int2 c0 = ldnt(&pk[e]);
        uint u0 = Xb[(c0.x << 6) + lane];
        float v0 = __int_as_float(c0.y);
        ax = fmaf(v0, bfl(u0), ax); ay = fmaf(v0, bfh(u0), ay);
    }
}

__device__ __forceinline__ void row_gather_bp(const int2* __restrict__ pk,
        int e, int end, const uint* __restrict__ Xb, int lane,
        float& sx, float& sy, float& qx, float& qy) {
    for (; e + 4 <= end; e += 4) {
        int2 c0 = ldnt(&pk[e]);     int2 c1 = ldnt(&pk[e + 1]);
        int2 c2 = ldnt(&pk[e + 2]); int2 c3 = ldnt(&pk[e + 3]);
        uint u0 = Xb[(c0.x << 6) + lane]; uint u1 = Xb[(c1.x << 6) + lane];
        uint u2 = Xb[(c2.x << 6) + lane]; uint u3 = Xb[(c3.x << 6) + lane];
        float v0 = __int_as_float(c0.y), v1 = __int_as_float(c1.y);
        float v2 = __int_as_float(c2.y), v3 = __int_as_float(c3.y);
        float x0 = bfl(u0), y0 = bfh(u0), x1 = bfl(u1), y1 = bfh(u1);
        float x2 = bfl(u2), y2 = bfh(u2), x3 = bfl(u3), y3 = bfh(u3);
        sx = fmaf(v0, x0, sx); sy = fmaf(v0, y0, sy);
        qx = fmaf(v0 * x0, x0, qx); qy = fmaf(v0 * y0, y0, qy);
        sx = fmaf(v1, x1, sx); sy = fmaf(v1, y1, sy);
        qx = fmaf(v1 * x1, x1, qx); qy = fmaf(v1 * y1, y1, qy);
        sx = fmaf(v2, x2, sx); sy = fmaf(v2, y2, sy);
        qx = fmaf(v2 * x2, x2, qx); qy = fmaf(v2 * y2, y2, qy);
        sx = fmaf(v3, x3, sx); sy = fmaf(v3, y3, sy);
        qx = fmaf(v3 * x3, x3, qx); qy = fmaf(v3 * y3, y3, qy);
    }
    for (; e < end; ++e) {
        int2 c0 = ldnt(&pk[e]);
        uint u0 = Xb[(c0.x << 6) + lane];
        float v0 = __int_as_float(c0.y);
        float x0 = bfl(u0), y0 = bfh(u0);
        sx = fmaf(v0, x0, sx); sy = fmaf(v0, y0, sy);
        qx = fmaf(v0 * x0, x0, qx); qy = fmaf(v0 * y0, y0, qy);
    }
}

__global__ __launch_bounds__(256) void spmm_bp2(const int* __restrict__ rpA,
        const int2* __restrict__ pkA, const int* __restrict__ rpB,
        const int2* __restrict__ pkB, const uint* __restrict__ Xb,
        uint* __restrict__ outb, int N) {
    int w = threadIdx.x >> 6, lane = threadIdx.x & 63;
    int stride = gridDim.x * 4;
    for (int row = blockIdx.x * 4 + w; row < N; row += stride) {
        float sax = 0.f, say = 0.f, qax = 0.f, qay = 0.f;
        float sbx = 0.f, sby = 0.f, qbx = 0.f, qby = 0.f;
        row_gather_bp(pkA, rpA[row], rpA[row + 1], Xb, lane, sax, say, qax, qay);
        row_gather_bp(pkB, rpB[row], rpB[row + 1], Xb, lane, sbx, sby, qbx, qby);
        float tx = 0.5f * ((sax * sax - qax) - (sbx * sbx - qbx));
        float ty = 0.5f * ((say * say - qay) - (sby * sby - qby));
        outb[((size_t)row << 6) + lane] = packbf2(tx, ty);
    }
}

__global__ __launch_bounds__(256) void spmm_out(const int* __restrict__ rp0,
        const int2* __restrict__ pk0, const int* __restrict__ rp5,
        const int2* __restrict__ pk5, const int* __restrict__ rp6,
        const int2* __restrict__ pk6, const uint* __restrict__ Pb,
        const uint* __restrict__ t1b, const uint* __restrict__ t2b,
        float* __restrict__ out, int N) {
    int w = threadIdx.x >> 6, lane = threadIdx.x & 63;
    int stride = gridDim.x * 4;
    for (int row = blockIdx.x * 4 + w; row < N; row += stride) {
        float a0x = 0.f, a0y = 0.f, a5x = 0.f, a5y = 0.f, a6x = 0.f, a6y = 0.f;
        row_gather_sum(pk0, rp0[row], rp0[row + 1], Pb,  lane, a0x, a0y);
        row_gather_sum(pk5, rp5[row], rp5[row + 1], t1b, lane, a5x, a5y);
        row_gather_sum(pk6, rp6[row], rp6[row + 1], t2b, lane, a6x, a6y);
        float rx = fmaxf(0.5f * a0x + 0.25f * a5x + 0.25f * a6x, 0.f);
        float ry = fmaxf(0.5f * a0y + 0.25f * a5y + 0.25f * a6y, 0.f);
        *(float2*)(out + ((size_t)row << 7) + (lane << 1)) = make_float2(rx, ry);
    }
}

// ---------------- launch ----------------

extern "C" void kernel_launch(void* const* d_in, const int* in_sizes, int n_in,
                              void* d_out, int out_size, void* d_ws, size_t ws_size,
                              hipStream_t stream) {
    (void)n_in; (void)out_size; (void)ws_size;
    const float* x   = (const float*)d_in[0];
    const float* Wa  = (const float*)d_in[1];
    const float* Wb  = (const float*)d_in[2];
    const float* w1  = (const float*)d_in[4];
    const float* b1  = (const float*)d_in[5];
    const float* w2  = (const float*)d_in[6];
    const int* rows  = (const int*)d_in[7];
    const int* cols  = (const int*)d_in[8];
    const float* vals = (const float*)d_in[9];
    float* out = (float*)d_out;

    const int N = in_sizes[0] / 256;
    const int E = in_sizes[7] / 7;
    const int NSB = (N + SBROWS - 1) >> SBSHIFT;
    const int nchunks = (E + CH - 1) / CH;

    // layout: Pb|t1b|t2b | pk (4E int2) | region{stage2 4E int2 / AB N*256 f32} |
    //         rp | lenTab | segPos | gtot | bbase
    uint* Pb  = (uint*)d_ws;
    uint* t1b = Pb + (size_t)N * 64;
    uint* t2b = t1b + (size_t)N * 64;
    int2* pk  = (int2*)(t2b + (size_t)N * 64);
    size_t regionFloats = (size_t)N * 256;
    if ((size_t)8 * E > regionFloats) regionFloats = (size_t)8 * E;
    int2* stage2 = pk + (size_t)4 * E;
    float* AB    = (float*)stage2;
    int* rp      = (int*)((float*)stage2 + regionFloats);
    int* lenTab  = rp + 4 * (size_t)(N + 1);
    int* segPos  = lenTab + (size_t)4 * NSB * nchunks;
    int* gtot    = segPos + (size_t)4 * NSB * nchunks;
    int* bbase   = gtot + (size_t)4 * NSB;

    dim3 b256(256);
    int sgrid = (N + 3) / 4;
    int pgrid = PGRID; if (pgrid > sgrid) pgrid = sgrid;

    gemm_kernel<<<(N + BM - 1) / BM, b256, 0, stream>>>(x, Wa, Wb, AB, N);
    attn_kernel<<<sgrid, b256, 0, stream>>>(AB, w1, b1, w2, Pb, N);

    auto build = [&](int4 map, int nsup) {
        hipMemsetAsync(gtot, 0, (size_t)nsup * NSB * sizeof(int), stream);
        count_chunk<<<dim3(nchunks, nsup), b256, 0, stream>>>(rows, map, lenTab, gtot,
                                                              NSB, nchunks, E);
        bucket_scanex<<<nsup, b256, 0, stream>>>(gtot, bbase, NSB);
        pos_scan<<<dim3(NSB, nsup), dim3(64), 0, stream>>>(lenTab, bbase, segPos, NSB, nchunks);
        place_chunk<<<dim3(nchunks, nsup), b256, 0, stream>>>(rows, cols, vals, map,
                                                              segPos, stage2, NSB, nchunks, E);
        fill_bucket<<<dim3(NSB, nsup), b256, 0, stream>>>(stage2, bbase, rp, pk, NSB, N, E);
    };

    const int NP1 = N + 1;

    // group A: slots {1,3,2,4}
    build(make_int4(1, 3, 2, 4), 4);
    spmm_bp2<<<pgrid, b256, 0, stream>>>(rp + 0 * NP1, pk + 0 * (size_t)E,
                                         rp + 1 * NP1, pk + 1 * (size_t)E, Pb, t1b, N);
    spmm_bp2<<<pgrid, b256, 0, stream>>>(rp + 2 * NP1, pk + 2 * (size_t)E,
                                         rp + 3 * NP1, pk + 3 * (size_t)E, Pb, t2b, N);

    // group B: slots {0,5,6}
    build(make_int4(0, 5, 6, 6), 3);
    spmm_out<<<pgrid, b256, 0, stream>>>(rp + 0 * NP1, pk + 0 * (size_t)E,
                                         rp + 1 * NP1, pk + 1 * (size_t)E,
                                         rp + 2 * NP1, pk + 2 * (size_t)E,
                                         Pb, t1b, t2b, out, N);
}